// Round 1
// 278.558 us; speedup vs baseline: 1.2645x; 1.2645x over previous
//
#include <hip/hip_runtime.h>
#include <hip/hip_bf16.h>

#define NPTS 500000
#define NGR  64
#define TR   256
#define NT2  ((NPTS + TR - 1) / TR)   // 1954
#define GRID2 256

typedef __bf16 bf16x8 __attribute__((ext_vector_type(8)));
typedef float f32x4 __attribute__((ext_vector_type(4)));
typedef unsigned int u32x4 __attribute__((ext_vector_type(4)));

// ---- workspace layout (bytes), all 16B aligned ----
#define OFF_BOUNDS 0        // int[65] : per-graph start offsets (batch is sorted)
#define OFF_OUTACC 6144     // u32[8192]: order-preserving max accum
#define OFF_CBIAS  38912    // f32[8192]: per-graph GEMM1 bias row
#define OFF_W1PT   71680    // f32[512] : W1[128:131]^T padded [128][4]
#define OFF_W1AT   73728    // u16[8192]: bf16 W1[64:128]^T [n=128][k=64], XOR-swizzled
#define OFF_W2T    90112    // u16[16384]: bf16 W2^T [n=128][k=128], XOR-swizzled

// order-preserving float->u32 map (max over u32 == max over float)
__device__ __forceinline__ unsigned mapf(float f) {
    union { float f; unsigned u; } v; v.f = f;
    return ((int)v.u >= 0) ? (v.u | 0x80000000u) : ~v.u;
}

#define GLOAD_LDS16(g, l) __builtin_amdgcn_global_load_lds(                 \
    (__attribute__((address_space(1))) void*)(g),                           \
    (__attribute__((address_space(3))) void*)(l), 16, 0, 0)

// ---- prep: W transposes (pre-swizzled for conflict-free LDS reads),
//            outacc init, per-graph range bounds via binary search ----
__global__ void k_prep(const float* __restrict__ W1,
                       const float* __restrict__ W2,
                       const int* __restrict__ batch,
                       unsigned short* __restrict__ W1aT,
                       unsigned short* __restrict__ W2T,
                       float* __restrict__ W1pT,
                       int* __restrict__ bounds,
                       unsigned* __restrict__ outacc) {
    int i = blockIdx.x * 256 + threadIdx.x;
    if (i < 8192) outacc[i] = 0u;
    if (blockIdx.x == 0 && threadIdx.x < 65) {
        int target = threadIdx.x;
        int lo = 0, hi = NPTS;
        while (lo < hi) {
            int mid = (lo + hi) >> 1;
            if (batch[mid] < target) lo = mid + 1; else hi = mid;
        }
        bounds[threadIdx.x] = lo;
    }
    if (i < 8192) {
        int n = i >> 6;
        unsigned short v = (unsigned short)(__builtin_bit_cast(unsigned, (float)(__bf16)W1[(64 + (i & 63)) * 128 + n]) >> 16);
        W1aT[i ^ ((n & 7) << 3)] = v;
    } else if (i < 8192 + 16384) {
        int j = i - 8192; int n = j >> 7, k = j & 127;
        unsigned short v = (unsigned short)(__builtin_bit_cast(unsigned, (float)(__bf16)W2[k * 128 + n]) >> 16);
        W2T[j ^ ((n & 7) << 3)] = v;
    } else if (i < 8192 + 16384 + 512) {
        int j = i - 24576; int n = j >> 2, q = j & 3;
        W1pT[j] = (q < 3) ? W1[(128 + q) * 128 + n] : 0.f;
    }
}

// ---- fused per-graph pass: COM (fp64) + argmin (truncated key) + cbias ----
// one block per graph over its contiguous [s,e) range; no atomics.
__global__ void k_pre(const float* __restrict__ pos,
                      const int* __restrict__ batch,
                      const float* __restrict__ x,
                      const float* __restrict__ W1,
                      const float* __restrict__ b1,
                      const float* __restrict__ lfr,
                      const int* __restrict__ bounds,
                      float* __restrict__ cbias,
                      float* __restrict__ outf) {
    __shared__ double sd[4][3];
    __shared__ unsigned long long sk[4];
    __shared__ double scom[3];
    __shared__ int sid;
    __shared__ float sposd[3];

    int g = blockIdx.x, t = threadIdx.x;
    int lane = t & 63, wv = t >> 6;
    int s = bounds[g], e = bounds[g + 1];

    // pass 1: fp64 position sums
    double sx = 0.0, sy = 0.0, sz = 0.0;
    for (int i = s + t; i < e; i += 256) {
        sx += (double)pos[i * 3 + 0];
        sy += (double)pos[i * 3 + 1];
        sz += (double)pos[i * 3 + 2];
    }
    #pragma unroll
    for (int m = 1; m < 64; m <<= 1) {
        sx += __shfl_xor(sx, m);
        sy += __shfl_xor(sy, m);
        sz += __shfl_xor(sz, m);
    }
    if (lane == 0) { sd[wv][0] = sx; sd[wv][1] = sy; sd[wv][2] = sz; }
    __syncthreads();
    if (t == 0) {
        double cnt = (double)(e - s);
        double rc = 1.0 / (cnt > 1.0 ? cnt : 1.0);
        scom[0] = (sd[0][0] + sd[1][0] + sd[2][0] + sd[3][0]) * rc;
        scom[1] = (sd[0][1] + sd[1][1] + sd[2][1] + sd[3][1]) * rc;
        scom[2] = (sd[0][2] + sd[1][2] + sd[2][2] + sd[3][2]) * rc;
    }
    __syncthreads();
    double cx = scom[0], cy = scom[1], cz = scom[2];

    // pass 2: argmin of fp64 d2, key = (trunc d2-bits) | id  (same as verified kernel)
    unsigned long long key = ~0ULL;
    for (int i = s + t; i < e; i += 256) {
        double dx = (double)pos[i * 3 + 0] - cx;
        double dy = (double)pos[i * 3 + 1] - cy;
        double dz = (double)pos[i * 3 + 2] - cz;
        double d2 = __builtin_fma(dx, dx, __builtin_fma(dy, dy, dz * dz));
        unsigned long long b = __builtin_bit_cast(unsigned long long, d2);
        unsigned long long k2 = (b & ~0xFFFFFULL) | (unsigned long long)i;
        key = k2 < key ? k2 : key;
    }
    #pragma unroll
    for (int m = 1; m < 64; m <<= 1) {
        unsigned long long o = __shfl_xor(key, m);
        key = o < key ? o : key;
    }
    if (lane == 0) sk[wv] = key;
    __syncthreads();
    if (t == 0) {
        unsigned long long k = sk[0];
        if (sk[1] < k) k = sk[1];
        if (sk[2] < k) k = sk[2];
        if (sk[3] < k) k = sk[3];
        int id = (int)(k & 0xFFFFFULL);
        if (id > NPTS - 1) id = NPTS - 1;
        sid = id;
    }
    __syncthreads();
    int id = sid;

    if (t < 3) {
        float p = pos[id * 3 + t];
        sposd[t] = p;
        outf[8192 + g * 3 + t] = p;
    }
    if (t == 4) outf[8192 + 192 + g] = (float)batch[id];
    if (t < 9) outf[8192 + 256 + g * 9 + t] = lfr[id * 9 + t];
    __syncthreads();

    // cbias (identical serial loop to verified k_fincb => bit-identical values)
    if (t < 128) {
        int c = t;
        float sv = b1[c];
        for (int k = 0; k < 64; ++k) {
            float xd = x[id * 64 + k];
            sv += xd * (W1[k * 128 + c] - W1[(64 + k) * 128 + c]);
        }
        sv -= sposd[0] * W1[128 * 128 + c] + sposd[1] * W1[129 * 128 + c] + sposd[2] * W1[130 * 128 + c];
        cbias[g * 128 + c] = sv;
    }
}

// ---- main: barrier-free tile loop. A direct global->VGPR (wave-private rows),
//      W1a/W2 staged once in LDS (swizzled), h in wave-private LDS stripe. ----
__global__ __launch_bounds__(512, 2) void k_main(
    const float* __restrict__ x,
    const float* __restrict__ pos,
    const int* __restrict__ batch,
    const unsigned short* __restrict__ W1aT,
    const unsigned short* __restrict__ W2T,
    const float* __restrict__ W1pT,
    const float* __restrict__ cbias,
    unsigned* __restrict__ outacc)
{
    // [0,16384): W1aT swizzled bf16 [128][64]
    // [16384,49152): W2T swizzled bf16 [128][128]
    // [49152,118784): h stripes: 8 waves x [32][136] bf16 (8704 B each)
    __shared__ alignas(16) unsigned char smem[118784];

    const int tid  = threadIdx.x;        // 0..511
    const int w    = tid >> 6;           // 0..7
    const int lane = tid & 63;
    const int quad = lane >> 4;
    const int mr   = lane & 15;

    // stage W once (linear copy; global layout is pre-swizzled)
    #pragma unroll
    for (int i = 0; i < 2; ++i)
        GLOAD_LDS16((const char*)W1aT + (i * 512 + tid) * 16,
                    (char*)smem + (i * 512 + tid) * 16);
    #pragma unroll
    for (int i = 0; i < 4; ++i)
        GLOAD_LDS16((const char*)W2T + (i * 512 + tid) * 16,
                    (char*)smem + 16384 + (i * 512 + tid) * 16);

    // tile-invariant: B-ext fragments for pos.W1p K-extension
    bf16x8 bfrE[8];
    #pragma unroll
    for (int t8 = 0; t8 < 8; ++t8) {
        f32x4 wp = *(const f32x4*)(W1pT + (t8 * 16 + mr) * 4);
        bf16x8 e = (bf16x8){0, 0, 0, 0, 0, 0, 0, 0};
        if (quad == 0) { e[0] = (__bf16)wp[0]; e[1] = (__bf16)wp[1]; e[2] = (__bf16)wp[2]; }
        bfrE[t8] = e;
    }

    __syncthreads();   // W staged; the only block-wide barrier in this kernel

    const unsigned short* sW1 = (const unsigned short*)smem;
    const unsigned short* sW2 = (const unsigned short*)(smem + 16384);
    __bf16* hsb = (__bf16*)(smem + 49152) + w * 4352;   // [32][136]

    for (int t = blockIdx.x; t < NT2; t += GRID2) {
        const int row0 = t * TR + 32 * w;   // this wave's 32 global rows

        // ---- A loads, direct global (issued first, 8x dwordx4) ----
        f32x4 av[2][4];
        #pragma unroll
        for (int u = 0; u < 2; ++u) {
            int gr2 = row0 + 16 * u + mr; if (gr2 > NPTS - 1) gr2 = NPTS - 1;
            const float* xp = x + gr2 * 64 + quad * 8;
            av[u][0] = *(const f32x4*)(xp);
            av[u][1] = *(const f32x4*)(xp + 4);
            av[u][2] = *(const f32x4*)(xp + 32);
            av[u][3] = *(const f32x4*)(xp + 36);
        }

        // ---- per-tile meta (overlaps A-load latency) ----
        int rowg[2][4]; bool rowv[2][4];
        #pragma unroll
        for (int u = 0; u < 2; ++u)
            #pragma unroll
            for (int r = 0; r < 4; ++r) {
                int gr = row0 + 16 * u + quad * 4 + r;
                rowv[u][r] = (gr < NPTS);
                rowg[u][r] = batch[gr < NPTS ? gr : NPTS - 1];
            }
        int gf = batch[row0 < NPTS ? row0 : NPTS - 1];
        int rl = row0 + 31; if (rl > NPTS - 1) rl = NPTS - 1;
        int gl = batch[rl];
        float cb0[8];
        #pragma unroll
        for (int t8 = 0; t8 < 8; ++t8) cb0[t8] = cbias[gf * 128 + t8 * 16 + mr];
        float pE[2][3];
        #pragma unroll
        for (int u = 0; u < 2; ++u) {
            int gp = row0 + 16 * u + mr; if (gp > NPTS - 1) gp = NPTS - 1;
            pE[u][0] = pos[gp * 3 + 0];
            pE[u][1] = pos[gp * 3 + 1];
            pE[u][2] = pos[gp * 3 + 2];
        }

        // ---- A fragments: afr[u][h][j] = x[row, h*32 + quad*8 + j] ----
        bf16x8 afr[2][2];
        #pragma unroll
        for (int u = 0; u < 2; ++u)
            #pragma unroll
            for (int h = 0; h < 2; ++h) {
                f32x4 va = av[u][2 * h], vb = av[u][2 * h + 1];
                bf16x8 a;
                a[0] = (__bf16)va[0]; a[1] = (__bf16)va[1]; a[2] = (__bf16)va[2]; a[3] = (__bf16)va[3];
                a[4] = (__bf16)vb[0]; a[5] = (__bf16)vb[1]; a[6] = (__bf16)vb[2]; a[7] = (__bf16)vb[3];
                afr[u][h] = a;
            }

        // ---- GEMM1 (B from swizzled LDS) + pos.W1p K-extension ----
        f32x4 acc[2][8];
        #pragma unroll
        for (int u = 0; u < 2; ++u)
            #pragma unroll
            for (int t8 = 0; t8 < 8; ++t8) acc[u][t8] = (f32x4){0.f, 0.f, 0.f, 0.f};
        #pragma unroll
        for (int t8 = 0; t8 < 8; ++t8) {
            int n = t8 * 16 + mr;
            int sw = (n & 7) << 3;
            bf16x8 bv0 = __builtin_bit_cast(bf16x8, *(const u32x4*)(sW1 + ((n * 64 + quad * 8) ^ sw)));
            bf16x8 bv1 = __builtin_bit_cast(bf16x8, *(const u32x4*)(sW1 + ((n * 64 + 32 + quad * 8) ^ sw)));
            #pragma unroll
            for (int u = 0; u < 2; ++u) {
                acc[u][t8] = __builtin_amdgcn_mfma_f32_16x16x32_bf16(afr[u][0], bv0, acc[u][t8], 0, 0, 0);
                acc[u][t8] = __builtin_amdgcn_mfma_f32_16x16x32_bf16(afr[u][1], bv1, acc[u][t8], 0, 0, 0);
            }
        }
        bf16x8 aE[2];
        #pragma unroll
        for (int u = 0; u < 2; ++u) {
            bf16x8 a = (bf16x8){0, 0, 0, 0, 0, 0, 0, 0};
            if (quad == 0) { a[0] = (__bf16)pE[u][0]; a[1] = (__bf16)pE[u][1]; a[2] = (__bf16)pE[u][2]; }
            aE[u] = a;
        }
        #pragma unroll
        for (int t8 = 0; t8 < 8; ++t8)
            #pragma unroll
            for (int u = 0; u < 2; ++u)
                acc[u][t8] = __builtin_amdgcn_mfma_f32_16x16x32_bf16(aE[u], bfrE[t8], acc[u][t8], 0, 0, 0);

        // ---- epilogue1: h = relu(acc + cbias[g]) -> wave-private LDS stripe ----
        #pragma unroll
        for (int u = 0; u < 2; ++u)
            #pragma unroll
            for (int r = 0; r < 4; ++r) {
                int lrow = 16 * u + quad * 4 + r;
                int g = rowg[u][r];
                bool odd = (g != gf);
                #pragma unroll
                for (int t8 = 0; t8 < 8; ++t8) {
                    float cbv = cb0[t8];
                    if (odd) cbv = cbias[g * 128 + t8 * 16 + mr];
                    float v = fmaxf(acc[u][t8][r] + cbv, 0.f);
                    hsb[lrow * 136 + t8 * 16 + mr] = (__bf16)v;
                }
            }
        // no barrier: GEMM2 reads only this wave's own stripe

        // ---- GEMM2 (A from own h stripe, B from swizzled LDS) ----
        f32x4 acc2[2][8];
        #pragma unroll
        for (int u = 0; u < 2; ++u)
            #pragma unroll
            for (int t8 = 0; t8 < 8; ++t8) acc2[u][t8] = (f32x4){0.f, 0.f, 0.f, 0.f};
        const unsigned short* hss = (const unsigned short*)hsb;
        #pragma unroll
        for (int kk = 0; kk < 4; ++kk) {
            bf16x8 a2[2];
            #pragma unroll
            for (int u = 0; u < 2; ++u)
                a2[u] = __builtin_bit_cast(bf16x8, *(const u32x4*)(hss + (16 * u + mr) * 136 + kk * 32 + quad * 8));
            #pragma unroll
            for (int t8 = 0; t8 < 8; ++t8) {
                int n = t8 * 16 + mr;
                bf16x8 bv = __builtin_bit_cast(bf16x8, *(const u32x4*)(sW2 + ((n * 128 + kk * 32 + quad * 8) ^ ((n & 7) << 3))));
                #pragma unroll
                for (int u = 0; u < 2; ++u)
                    acc2[u][t8] = __builtin_amdgcn_mfma_f32_16x16x32_bf16(a2[u], bv, acc2[u][t8], 0, 0, 0);
            }
        }

        // ---- epilogue2: per-graph column max -> global atomicMax ----
        for (int g = gf; g <= gl; ++g) {
            #pragma unroll
            for (int t8 = 0; t8 < 8; ++t8) {
                float m = -INFINITY;
                #pragma unroll
                for (int u = 0; u < 2; ++u)
                    #pragma unroll
                    for (int r = 0; r < 4; ++r)
                        if (rowv[u][r] && rowg[u][r] == g) m = fmaxf(m, acc2[u][t8][r]);
                m = fmaxf(m, __shfl_xor(m, 16));
                m = fmaxf(m, __shfl_xor(m, 32));
                unsigned mb = __builtin_bit_cast(unsigned, m);
                if (quad == 0 && mb != 0xFF800000u)
                    atomicMax(&outacc[g * 128 + t8 * 16 + mr], mapf(m));
            }
        }
    }
}

__global__ void k_out(const unsigned* __restrict__ outacc,
                      const float* __restrict__ b2v,
                      float* __restrict__ outf) {
    int i = blockIdx.x * 256 + threadIdx.x;   // 8192 threads
    unsigned key = outacc[i];
    float v;
    if (key == 0u) {
        v = -300.f;   // diagnostic: never updated
    } else {
        unsigned bits = (key & 0x80000000u) ? (key & 0x7FFFFFFFu) : ~key;
        union { unsigned u; float f; } c; c.u = bits; v = c.f;
    }
    outf[i] = v + b2v[i & 127];
}

extern "C" void kernel_launch(void* const* d_in, const int* in_sizes, int n_in,
                              void* d_out, int out_size, void* d_ws, size_t ws_size,
                              hipStream_t stream) {
    const float* x   = (const float*)d_in[0];
    const float* pos = (const float*)d_in[1];
    const int*   bat = (const int*)d_in[2];
    const float* lfr = (const float*)d_in[3];
    const float* W1  = (const float*)d_in[4];
    const float* b1  = (const float*)d_in[5];
    const float* W2  = (const float*)d_in[6];
    const float* b2v = (const float*)d_in[7];
    float* outf = (float*)d_out;

    char* ws = (char*)d_ws;
    int*            bounds = (int*)(ws + OFF_BOUNDS);
    unsigned*       outacc = (unsigned*)(ws + OFF_OUTACC);
    float*          cbias  = (float*)(ws + OFF_CBIAS);
    float*          W1pT   = (float*)(ws + OFF_W1PT);
    unsigned short* W1aT   = (unsigned short*)(ws + OFF_W1AT);
    unsigned short* W2T    = (unsigned short*)(ws + OFF_W2T);

    k_prep<<<98, 256, 0, stream>>>(W1, W2, bat, W1aT, W2T, W1pT, bounds, outacc);
    k_pre<<<64, 256, 0, stream>>>(pos, bat, x, W1, b1, lfr, bounds, cbias, outf);
    k_main<<<GRID2, 512, 0, stream>>>(x, pos, bat, W1aT, W2T, W1pT, cbias, outacc);
    k_out<<<32, 256, 0, stream>>>(outacc, b2v, outf);
}